// Round 9
// baseline (309.846 us; speedup 1.0000x reference)
//
#include <hip/hip_runtime.h>
#include <hip/hip_bf16.h>

typedef __attribute__((ext_vector_type(8))) short short8;
typedef __attribute__((ext_vector_type(4))) short short4v;
typedef __attribute__((ext_vector_type(4))) float f32x4;
typedef __attribute__((ext_vector_type(4))) float float4v;

#define S_LEN 2048
#define DMODEL 2048
#define N_HEADS 16
#define HEAD_DIM 128

__device__ __forceinline__ float bf2f(__hip_bfloat16 b) { return __bfloat162float(b); }
__device__ __forceinline__ __hip_bfloat16 f2bf(float f) { return __float2bfloat16(f); }
__device__ __forceinline__ short bfs(float f) {
    union { __hip_bfloat16 b; short s; } x; x.b = __float2bfloat16(f); return x.s;
}
__device__ __forceinline__ float sbf(short s) {
    union { short s; __hip_bfloat16 b; } x; x.s = s; return __bfloat162float(x.b);
}

#if __has_builtin(__builtin_amdgcn_global_load_lds)
#define HAVE_ASYNC_LDS 1
#else
#define HAVE_ASYNC_LDS 0
#endif

__device__ __forceinline__ void stage16(const __hip_bfloat16* g, __hip_bfloat16* ldsbase, int lane) {
#if HAVE_ASYNC_LDS
    __builtin_amdgcn_global_load_lds(
        (const __attribute__((address_space(1))) unsigned int*)g,
        (__attribute__((address_space(3))) unsigned int*)ldsbase,
        16, 0, 0);
#else
    *(short8*)((char*)ldsbase + lane * 16) = *(const short8*)g;
#endif
}

// ---------------- prep: 4 weight transposes (f32->bf16) + x conversion ----------------
__global__ __launch_bounds__(256) void prep(const float* __restrict__ x,
                                            const float* __restrict__ w0,
                                            const float* __restrict__ w1,
                                            const float* __restrict__ w2,
                                            const float* __restrict__ w3,
                                            __hip_bfloat16* __restrict__ xb,
                                            __hip_bfloat16* __restrict__ o0,
                                            __hip_bfloat16* __restrict__ o1,
                                            __hip_bfloat16* __restrict__ o2,
                                            __hip_bfloat16* __restrict__ o3) {
    const int z = blockIdx.z;
    const int tid = threadIdx.x;
    if (z == 4) {
        size_t base = (((size_t)blockIdx.y * 32 + blockIdx.x) * 256 + tid) * 16;
        for (int i = 0; i < 4; ++i) {
            float4v v = *(const float4v*)(x + base + i * 4);
            short4v p;
            p.x = bfs(v.x); p.y = bfs(v.y); p.z = bfs(v.z); p.w = bfs(v.w);
            *(short4v*)((short*)xb + base + i * 4) = p;
        }
        return;
    }
    const float* in = (z == 0) ? w0 : (z == 1) ? w1 : (z == 2) ? w2 : w3;
    __hip_bfloat16* out = (z == 0) ? o0 : (z == 1) ? o1 : (z == 2) ? o2 : o3;
    __shared__ short tile[64][68];
    const int bx = blockIdx.x * 64;
    const int by = blockIdx.y * 64;
    const int c4 = (tid & 15) * 4;
    for (int rr = 0; rr < 4; ++rr) {
        int r = (tid >> 4) + rr * 16;
        float4v v = *(const float4v*)(in + (size_t)(by + r) * DMODEL + bx + c4);
        short4v p;
        p.x = bfs(v.x); p.y = bfs(v.y); p.z = bfs(v.z); p.w = bfs(v.w);
        *(short4v*)&tile[r][c4] = p;
    }
    __syncthreads();
    const int oc = tid >> 2;
    const int s0 = (tid & 3) * 16;
    short8 a, b;
    for (int i = 0; i < 8; ++i) ((short*)&a)[i] = tile[s0 + i][oc];
    for (int i = 0; i < 8; ++i) ((short*)&b)[i] = tile[s0 + 8 + i][oc];
    *(short8*)((short*)out + (size_t)(bx + oc) * DMODEL + by + s0) = a;
    *(short8*)((short*)out + (size_t)(bx + oc) * DMODEL + by + s0 + 8) = b;
}

// ---------------- split-K QKV GEMM (R8, unchanged) ----------------
__global__ __launch_bounds__(256) void gemm_qkv_sk(const __hip_bfloat16* __restrict__ A,
                                                   const __hip_bfloat16* __restrict__ Bq,
                                                   const __hip_bfloat16* __restrict__ Bk,
                                                   const __hip_bfloat16* __restrict__ Bv,
                                                   __hip_bfloat16* __restrict__ Q0,
                                                   __hip_bfloat16* __restrict__ Q1,
                                                   __hip_bfloat16* __restrict__ K0,
                                                   __hip_bfloat16* __restrict__ K1,
                                                   __hip_bfloat16* __restrict__ V0t,
                                                   __hip_bfloat16* __restrict__ V1t) {
    __shared__ alignas(16) __hip_bfloat16 As[128 * 32];
    __shared__ alignas(16) __hip_bfloat16 Bs[128 * 32];
    const int bx = blockIdx.x;
    const int which = bx >> 5;
    const int kh = (bx >> 4) & 1;
    const __hip_bfloat16* Bt = (which == 0) ? Bq : (which == 1) ? Bk : Bv;
    const int tid = threadIdx.x;
    const int wave = tid >> 6;
    const int lane = tid & 63;
    const int lane15 = lane & 15;
    const int quad = lane >> 4;
    const int m0 = blockIdx.y * 128;
    const int n0 = (bx & 15) * 128;
    const int wm = (wave >> 1) * 64;
    const int wn = (wave & 1) * 64;

    f32x4 acc[4][4];
    for (int i = 0; i < 4; ++i)
        for (int j = 0; j < 4; ++j)
            acc[i][j] = {0.f, 0.f, 0.f, 0.f};

    const int rA = lane >> 2;
    const int cA = (lane & 3) * 8;
    const int kbeg = kh * 1024;

    for (int k0 = kbeg; k0 < kbeg + 1024; k0 += 32) {
        __syncthreads();
        for (int c = 0; c < 4; ++c) {
            int chunk = wave * 4 + c;
            if (chunk < 8) {
                int r = chunk * 16 + rA;
                stage16(A + (size_t)(m0 + r) * DMODEL + k0 + cA, As + chunk * 512, lane);
            } else {
                int r = (chunk - 8) * 16 + rA;
                stage16(Bt + (size_t)(n0 + r) * DMODEL + k0 + cA, Bs + (chunk - 8) * 512, lane);
            }
        }
#if HAVE_ASYNC_LDS
        asm volatile("s_waitcnt vmcnt(0)" ::: "memory");
#endif
        __syncthreads();

        short8 af[4], bfr[4];
        for (int mt = 0; mt < 4; ++mt)
            af[mt] = *(const short8*)(As + (wm + mt * 16 + lane15) * 32 + quad * 8);
        for (int nt = 0; nt < 4; ++nt)
            bfr[nt] = *(const short8*)(Bs + (wn + nt * 16 + lane15) * 32 + quad * 8);
        for (int mt = 0; mt < 4; ++mt)
            for (int nt = 0; nt < 4; ++nt)
                acc[mt][nt] = __builtin_amdgcn_mfma_f32_16x16x32_bf16(af[mt], bfr[nt], acc[mt][nt], 0, 0, 0);
    }

    if (which < 2) {
        __hip_bfloat16* C = (which == 0) ? (kh ? Q1 : Q0) : (kh ? K1 : K0);
        for (int mt = 0; mt < 4; ++mt)
            for (int nt = 0; nt < 4; ++nt)
                for (int i = 0; i < 4; ++i) {
                    int row = m0 + wm + mt * 16 + quad * 4 + i;
                    int col = n0 + wn + nt * 16 + lane15;
                    C[(size_t)row * DMODEL + col] = f2bf(acc[mt][nt][i]);
                }
    } else {
        __hip_bfloat16* Vp = kh ? V1t : V0t;
        for (int mt = 0; mt < 4; ++mt) {
            int rowbase = m0 + wm + mt * 16 + quad * 4;
            for (int nt = 0; nt < 4; ++nt) {
                int col = n0 + wn + nt * 16 + lane15;
                short4v pk;
                pk.x = bfs(acc[mt][nt][0]);
                pk.y = bfs(acc[mt][nt][1]);
                pk.z = bfs(acc[mt][nt][2]);
                pk.w = bfs(acc[mt][nt][3]);
                *(short4v*)((short*)Vp + (size_t)col * S_LEN + rowbase) = pk;
            }
        }
    }
}

// ---------------- reduce partials: Q,K with RoPE; V plain (R8, unchanged) ----------------
__global__ __launch_bounds__(256) void reduce_rope(__hip_bfloat16* __restrict__ Q0,
                                                   const __hip_bfloat16* __restrict__ Q1,
                                                   __hip_bfloat16* __restrict__ K0,
                                                   const __hip_bfloat16* __restrict__ K1,
                                                   __hip_bfloat16* __restrict__ V0,
                                                   const __hip_bfloat16* __restrict__ V1,
                                                   const float* __restrict__ fc,
                                                   const float* __restrict__ fs) {
    const int z = blockIdx.z;
    __hip_bfloat16* P0 = (z == 0) ? Q0 : (z == 1) ? K0 : V0;
    const __hip_bfloat16* P1 = (z == 0) ? Q1 : (z == 1) ? K1 : V1;
    size_t i0 = ((size_t)blockIdx.x * 256 + threadIdx.x) * 8;
    short8 a = *(const short8*)((const short*)P0 + i0);
    short8 b = *(const short8*)((const short*)P1 + i0);
    float s[8];
    for (int i = 0; i < 8; ++i) s[i] = sbf(((short*)&a)[i]) + sbf(((short*)&b)[i]);
    short8 o;
    if (z < 2) {
        int row = (int)(i0 >> 11);
        int col = (int)(i0 & 2047);
        int j0 = (col & 127) >> 1;
        for (int p = 0; p < 4; ++p) {
            float c = fc[row * 64 + j0 + p];
            float sn = fs[row * 64 + j0 + p];
            float e = s[2 * p], od = s[2 * p + 1];
            ((short*)&o)[2 * p]     = bfs(e * c - od * sn);
            ((short*)&o)[2 * p + 1] = bfs(e * sn + od * c);
        }
    } else {
        for (int i = 0; i < 8; ++i) ((short*)&o)[i] = bfs(s[i]);
    }
    *(short8*)((short*)P0 + i0) = o;
}

// ---------------- flash attention, split-key, 128-row q-blocks ----------------
// Fixed-base softmax (softcap bounds scores) => partial unnormalized O and l just add.
// 512 blocks: u=bx&255: head=u&15, qp=u>>4; half=bx>>8; qb = half ? 15-qp : qp.
// Key tiles [t0,t1): half0 [0,2qb+2), half1 [2qb+2,4qb+4) — per-CU pair sums to 34 tiles.
// 4 waves x 32 q-rows (2 rowgroups). Of0/Of1: separate 16MB f32 buffers; Lf: [2][16][2048].
__global__ __launch_bounds__(256) void flash_attn_sk(const __hip_bfloat16* __restrict__ Q,
                                                     const __hip_bfloat16* __restrict__ Kb,
                                                     const __hip_bfloat16* __restrict__ Vt,
                                                     float* __restrict__ Of0,
                                                     float* __restrict__ Of1,
                                                     float* __restrict__ Lf) {
    __shared__ alignas(16) short Ks[32][136];
    __shared__ alignas(16) short Vs[128][40];
    __shared__ alignas(16) short Pl[4][32][40];
    const int tid = threadIdx.x;
    const int wave = tid >> 6;
    const int lane = tid & 63;
    const int lane15 = lane & 15;
    const int quad = lane >> 4;
    const int bx = blockIdx.x;
    const int u = bx & 255;
    const int head = u & 15;
    const int qp = u >> 4;
    const int half = bx >> 8;
    const int qb = half ? (15 - qp) : qp;
    const int q0w = qb * 128 + wave * 32;
    const int t0 = half ? (2 * qb + 2) : 0;
    const int t1 = half ? (4 * qb + 4) : (2 * qb + 2);
    const float K1 = 0.08838834764831845f * (1.0f / 25.0f);

    short8 qf[2][4];
    for (int rg = 0; rg < 2; ++rg) {
        const __hip_bfloat16* Qh = Q + (size_t)(q0w + rg * 16) * DMODEL + head * HEAD_DIM;
        for (int kk = 0; kk < 4; ++kk)
            qf[rg][kk] = *(const short8*)(Qh + (size_t)lane15 * DMODEL + kk * 32 + quad * 8);
    }

    f32x4 acc[2][8];
    for (int rg = 0; rg < 2; ++rg)
        for (int i = 0; i < 8; ++i) acc[rg][i] = {0.f, 0.f, 0.f, 0.f};
    float lpart[2][4] = {{0.f, 0.f, 0.f, 0.f}, {0.f, 0.f, 0.f, 0.f}};

    const int krow = tid >> 3, kcol = (tid & 7) * 16;
    const int vrow = tid >> 1, vcol = (tid & 1) * 16;
    const __hip_bfloat16* Kg = Kb + (size_t)krow * DMODEL + head * HEAD_DIM + kcol;
    const __hip_bfloat16* Vg = Vt + (size_t)(head * HEAD_DIM + vrow) * S_LEN + vcol;

    short8 gk0 = *(const short8*)(Kg + (size_t)(t0 * 32) * DMODEL);
    short8 gk1 = *(const short8*)(Kg + (size_t)(t0 * 32) * DMODEL + 8);
    short8 gv0 = *(const short8*)(Vg + t0 * 32);
    short8 gv1 = *(const short8*)(Vg + t0 * 32 + 8);

    for (int kt = t0; kt < t1; ++kt) {
        const int kb = kt * 32;
        __syncthreads();
        *(short8*)&Ks[krow][kcol] = gk0;
        *(short8*)&Ks[krow][kcol + 8] = gk1;
        *(short8*)&Vs[vrow][vcol] = gv0;
        *(short8*)&Vs[vrow][vcol + 8] = gv1;
        __syncthreads();

        if (kt + 1 < t1) {
            const __hip_bfloat16* Kg2 = Kg + (size_t)(kb + 32) * DMODEL;
            const __hip_bfloat16* Vg2 = Vg + kb + 32;
            gk0 = *(const short8*)(Kg2);
            gk1 = *(const short8*)(Kg2 + 8);
            gv0 = *(const short8*)(Vg2);
            gv1 = *(const short8*)(Vg2 + 8);
        }

        for (int rg = 0; rg < 2; ++rg) {
            const int q0r = q0w + rg * 16;
            if (kb > q0r + 15) continue;  // fully masked for this rowgroup

            f32x4 sc[2];
            sc[0] = {0.f, 0.f, 0.f, 0.f};
            sc[1] = {0.f, 0.f, 0.f, 0.f};
            for (int c = 0; c < 2; ++c)
                for (int kk = 0; kk < 4; ++kk) {
                    short8 kf = *(const short8*)&Ks[c * 16 + lane15][kk * 32 + quad * 8];
                    sc[c] = __builtin_amdgcn_mfma_f32_16x16x32_bf16(qf[rg][kk], kf, sc[c], 0, 0, 0);
                }

            const bool masked = (kb + 31 > q0r);
            const int key0 = kb + lane15;
            const int key1 = kb + 16 + lane15;
            for (int i = 0; i < 4; ++i) {
                float e0 = __expf(sc[0][i] * K1);
                float e1 = __expf(sc[1][i] * K1);
                float c0 = __builtin_fmaf(-100.0f, __builtin_amdgcn_rcpf(e0 + 1.0f), 40.0f);
                float c1 = __builtin_fmaf(-100.0f, __builtin_amdgcn_rcpf(e1 + 1.0f), 40.0f);
                float p0 = __expf(c0);
                float p1 = __expf(c1);
                if (masked) {
                    int q = q0r + quad * 4 + i;
                    if (key0 > q) p0 = 0.f;
                    if (key1 > q) p1 = 0.f;
                }
                short b0 = bfs(p0), b1 = bfs(p1);
                lpart[rg][i] += sbf(b0) + sbf(b1);
                Pl[wave][rg * 16 + quad * 4 + i][lane15] = b0;
                Pl[wave][rg * 16 + quad * 4 + i][16 + lane15] = b1;
            }
            asm volatile("s_waitcnt lgkmcnt(0)" ::: "memory");
            short8 pf = *(const short8*)&Pl[wave][rg * 16 + lane15][quad * 8];
            asm volatile("" ::: "memory");
            for (int nt = 0; nt < 8; ++nt) {
                short8 vf = *(const short8*)&Vs[nt * 16 + lane15][quad * 8];
                acc[rg][nt] = __builtin_amdgcn_mfma_f32_16x16x32_bf16(pf, vf, acc[rg][nt], 0, 0, 0);
            }
        }
    }

    float* Ofh = half ? Of1 : Of0;
    float* Lfh = Lf + (size_t)half * N_HEADS * S_LEN;
    for (int rg = 0; rg < 2; ++rg)
        for (int i = 0; i < 4; ++i) {
            float l = lpart[rg][i];
            l += __shfl_xor(l, 1, 64);
            l += __shfl_xor(l, 2, 64);
            l += __shfl_xor(l, 4, 64);
            l += __shfl_xor(l, 8, 64);
            int row = q0w + rg * 16 + quad * 4 + i;
            if (lane15 == 0) Lfh[head * S_LEN + row] = l;
            for (int nt = 0; nt < 8; ++nt) {
                int col = head * HEAD_DIM + nt * 16 + lane15;
                Ofh[(size_t)row * DMODEL + col] = acc[rg][nt][i];
            }
        }
}

// ---------------- combine flash partials -> attn (bf16) ----------------
__global__ __launch_bounds__(256) void combine_attn(const float* __restrict__ Of0,
                                                    const float* __restrict__ Of1,
                                                    const float* __restrict__ Lf,
                                                    __hip_bfloat16* __restrict__ attn) {
    size_t i0 = ((size_t)blockIdx.x * 256 + threadIdx.x) * 8;
    int row = (int)(i0 >> 11);
    int head = ((int)(i0 & 2047)) >> 7;
    float l = Lf[head * S_LEN + row] + Lf[N_HEADS * S_LEN + head * S_LEN + row];
    float inv = 1.0f / l;
    short8 o;
    for (int i = 0; i < 8; ++i)
        ((short*)&o)[i] = bfs((Of0[i0 + i] + Of1[i0 + i]) * inv);
    *(short8*)((short*)attn + i0) = o;
}

// ---------------- split-K final GEMM (f32 partials) ----------------
__global__ __launch_bounds__(256) void gemm_out_sk(const __hip_bfloat16* __restrict__ A,
                                                   const __hip_bfloat16* __restrict__ Bt,
                                                   float* __restrict__ P0,
                                                   float* __restrict__ P1) {
    __shared__ alignas(16) __hip_bfloat16 As[128 * 32];
    __shared__ alignas(16) __hip_bfloat16 Bs[64 * 32];
    const int tid = threadIdx.x;
    const int wave = tid >> 6;
    const int lane = tid & 63;
    const int lane15 = lane & 15;
    const int quad = lane >> 4;
    const int m0 = blockIdx.y * 128;
    const int n0 = blockIdx.x * 64;
    const int wm = (wave >> 1) * 64;
    const int wn = (wave & 1) * 32;
    float* P = blockIdx.z ? P1 : P0;
    const int kbeg = blockIdx.z * 1024;

    f32x4 acc[4][2];
    for (int i = 0; i < 4; ++i)
        for (int j = 0; j < 2; ++j)
            acc[i][j] = {0.f, 0.f, 0.f, 0.f};

    const int rA = lane >> 2;
    const int cA = (lane & 3) * 8;

    for (int k0 = kbeg; k0 < kbeg + 1024; k0 += 32) {
        __syncthreads();
        for (int c = 0; c < 3; ++c) {
            int chunk = wave * 3 + c;
            if (chunk < 8) {
                int r = chunk * 16 + rA;
                stage16(A + (size_t)(m0 + r) * DMODEL + k0 + cA, As + chunk * 512, lane);
            } else {
                int r = (chunk - 8) * 16 + rA;
                stage16(Bt + (size_t)(n0 + r) * DMODEL + k0 + cA, Bs + (chunk - 8) * 512, lane);
            }
        }
#if HAVE_ASYNC_LDS
        asm volatile("s_waitcnt vmcnt(0)" ::: "memory");
#endif
        __syncthreads();

        short8 af[4], bfr[2];
        for (int mt = 0; mt < 4; ++mt)
            af[mt] = *(const short8*)(As + (wm + mt * 16 + lane15) * 32 + quad * 8);
        for (int nt = 0; nt < 2; ++nt)
            bfr[nt] = *(const short8*)(Bs + (wn + nt * 16 + lane15) * 32 + quad * 8);
        for (int mt = 0; mt < 4; ++mt)
            for (int nt = 0; nt < 2; ++nt)
                acc[mt][nt] = __builtin_amdgcn_mfma_f32_16x16x32_bf16(af[mt], bfr[nt], acc[mt][nt], 0, 0, 0);
    }

    for (int mt = 0; mt < 4; ++mt)
        for (int nt = 0; nt < 2; ++nt)
            for (int i = 0; i < 4; ++i) {
                int row = m0 + wm + mt * 16 + quad * 4 + i;
                int col = n0 + wn + nt * 16 + lane15;
                P[(size_t)row * DMODEL + col] = acc[mt][nt][i];
            }
}

// ---------------- combine gemm_out partials -> out (f32) ----------------
__global__ __launch_bounds__(256) void combine_out(const float* __restrict__ P0,
                                                   const float* __restrict__ P1,
                                                   float* __restrict__ out) {
    size_t i0 = ((size_t)blockIdx.x * 256 + threadIdx.x) * 8;
    for (int i = 0; i < 8; i += 4) {
        float4v a = *(const float4v*)(P0 + i0 + i);
        float4v b = *(const float4v*)(P1 + i0 + i);
        float4v o;
        o.x = a.x + b.x; o.y = a.y + b.y; o.z = a.z + b.z; o.w = a.w + b.w;
        *(float4v*)(out + i0 + i) = o;
    }
}

extern "C" void kernel_launch(void* const* d_in, const int* in_sizes, int n_in,
                              void* d_out, int out_size, void* d_ws, size_t ws_size,
                              hipStream_t stream) {
    const float* x  = (const float*)d_in[0];
    const float* wq = (const float*)d_in[1];
    const float* wk = (const float*)d_in[2];
    const float* wv = (const float*)d_in[3];
    const float* wo = (const float*)d_in[4];
    const float* fc = (const float*)d_in[5];
    const float* fs = (const float*)d_in[6];
    float* out = (float*)d_out;

    char* ws = (char*)d_ws;
    const size_t MB8 = (size_t)2048 * 2048 * sizeof(__hip_bfloat16);
    // 10 slots s0..s9 = 80 MB (availability proven in R8: split-K path ran and passed).
    __hip_bfloat16* wq_t = (__hip_bfloat16*)(ws + 0 * MB8);
    __hip_bfloat16* wk_t = (__hip_bfloat16*)(ws + 1 * MB8);
    __hip_bfloat16* wv_t = (__hip_bfloat16*)(ws + 2 * MB8);
    __hip_bfloat16* wo_t = (__hip_bfloat16*)(ws + 3 * MB8);
    __hip_bfloat16* s4   = (__hip_bfloat16*)(ws + 4 * MB8);
    __hip_bfloat16* s5   = (__hip_bfloat16*)(ws + 5 * MB8);
    __hip_bfloat16* s6   = (__hip_bfloat16*)(ws + 6 * MB8);
    __hip_bfloat16* s7   = (__hip_bfloat16*)(ws + 7 * MB8);
    __hip_bfloat16* s8   = (__hip_bfloat16*)(ws + 8 * MB8);
    __hip_bfloat16* s9   = (__hip_bfloat16*)(ws + 9 * MB8);
    __hip_bfloat16* x_bf = (__hip_bfloat16*)d_out;   // dead after gemm_qkv_sk

    prep<<<dim3(32, 32, 5), 256, 0, stream>>>(x, wq, wk, wv, wo, x_bf, wq_t, wk_t, wv_t, wo_t);

    // QKV split-K partials: Q0=s4 Q1=s7 K0=s5 K1=s8 V0t=s6 V1t=s9
    gemm_qkv_sk<<<dim3(96, 16), 256, 0, stream>>>(x_bf, wq_t, wk_t, wv_t,
                                                  s4, s7, s5, s8, s6, s9);
    // Q->s4, K->s5, Vt->s6 (s7,s8,s9 dead after)
    reduce_rope<<<dim3(2048, 1, 3), 256, 0, stream>>>(s4, s7, s5, s8, s6, s9, fc, fs);

    // Flash split-key. Of0 = s7+s8 (16MB f32). Of1 = s0+s1 (wq_t/wk_t dead). Lf = s9 (256KB).
    float* Of0 = (float*)s7;
    float* Of1 = (float*)wq_t;
    float* Lf  = (float*)s9;
    flash_attn_sk<<<512, 256, 0, stream>>>(s4, s5, s6, Of0, Of1, Lf);

    // attn (bf16) -> s2 (wv_t dead)
    __hip_bfloat16* attn = wv_t;
    combine_attn<<<2048, 256, 0, stream>>>(Of0, Of1, Lf, attn);

    // gemm_out split-K: f32 partials P0 = s4+s5 (Q,K dead), P1 = s6+s7 (Vt,Of0 dead)
    float* P0 = (float*)s4;
    float* P1 = (float*)s6;
    gemm_out_sk<<<dim3(32, 16, 2), 256, 0, stream>>>(attn, wo_t, P0, P1);
    combine_out<<<2048, 256, 0, stream>>>(P0, P1, out);
}